// Round 1
// baseline (1008.427 us; speedup 1.0000x reference)
//
#include <hip/hip_runtime.h>
#include <hip/hip_bf16.h>

typedef unsigned short u16;
typedef __attribute__((ext_vector_type(8))) short s16x8;
typedef __attribute__((ext_vector_type(4))) float f32x4;

#define MFMA16(a, b, c) __builtin_amdgcn_mfma_f32_16x16x32_bf16((a), (b), (c), 0, 0, 0)

__device__ __forceinline__ float b2f(u16 u) {
    union { float f; unsigned int i; } c; c.i = ((unsigned int)u) << 16; return c.f;
}
__device__ __forceinline__ u16 f2b(float f) {
    union { float f; unsigned int i; } c; c.f = f;
    unsigned int i = c.i;
    return (u16)((i + 0x7fffu + ((i >> 16) & 1u)) >> 16);  // RNE
}

// Load 8 consecutive elements of an EXTERNAL tensor (runtime dtype) as bf16.
__device__ __forceinline__ s16x8 load8b(const void* base, size_t idx, int isf32) {
    if (!isf32) {
        return *(const s16x8*)((const u16*)base + idx);
    } else {
        const float* p = (const float*)base + idx;
        f32x4 a = *(const f32x4*)p;
        f32x4 b = *(const f32x4*)(p + 4);
        s16x8 v;
        v[0] = (short)f2b(a[0]); v[1] = (short)f2b(a[1]);
        v[2] = (short)f2b(a[2]); v[3] = (short)f2b(a[3]);
        v[4] = (short)f2b(b[0]); v[5] = (short)f2b(b[1]);
        v[6] = (short)f2b(b[2]); v[7] = (short)f2b(b[3]);
        return v;
    }
}
__device__ __forceinline__ float loadsc(const void* base, size_t idx, int isf32) {
    return isf32 ? ((const float*)base)[idx] : b2f(((const u16*)base)[idx]);
}
// Non-temporal scalar load (streaming read-once data: the mask).
__device__ __forceinline__ float loadsc_nt(const void* base, size_t idx, int isf32) {
    if (isf32) return __builtin_nontemporal_load((const float*)base + idx);
    u16 u = __builtin_nontemporal_load((const u16*)base + idx);
    return b2f(u);
}

// ---------------------------------------------------------------------------
// Dtype detection: read q's first 1024 u16 words as bf16. Real-bf16 N(0,1)
// data has exponent in [110,135] essentially always; fp32 data read as u16
// halves gives ~55% sane words. Flag drives BOTH input and output dtype.
// ---------------------------------------------------------------------------
__global__ __launch_bounds__(64) void k_detect(const u16* __restrict__ q, int* __restrict__ flag) {
    int t = threadIdx.x;
    int cnt = 0;
#pragma unroll
    for (int i = 0; i < 16; i++) {
        u16 u = q[t * 16 + i];
        int e = (u >> 7) & 0xFF;
        cnt += (e >= 110 && e <= 135) ? 1 : 0;
    }
#pragma unroll
    for (int off = 32; off > 0; off >>= 1) cnt += __shfl_down(cnt, off);
    if (t == 0) *flag = (cnt < 850) ? 1 : 0;  // 1 => fp32 tensors
}

// ---------------------------------------------------------------------------
// Transpose the 4 weight matrices (768x768) to WT[n][k] (k-contig) in bf16.
// ---------------------------------------------------------------------------
__global__ __launch_bounds__(256) void k_transpose(
    const void* __restrict__ w0, const void* __restrict__ w1,
    const void* __restrict__ w2, const void* __restrict__ w3,
    u16* __restrict__ wt, const int* __restrict__ flag)
{
    __shared__ __align__(16) u16 T[64 * 65];
    const int isf32 = *flag;
    const int z = blockIdx.z;
    const void* W = (z == 0) ? w0 : (z == 1) ? w1 : (z == 2) ? w2 : w3;
    u16* WT = wt + (size_t)z * 589824;
    const int n0 = blockIdx.x * 64, k0 = blockIdx.y * 64;
    const int t = threadIdx.x;
    const int r = t >> 3, c = (t & 7) * 8;
    for (int rr = r; rr < 64; rr += 32) {
        s16x8 v = load8b(W, (size_t)(k0 + rr) * 768 + n0 + c, isf32);
#pragma unroll
        for (int j = 0; j < 8; j++) T[(c + j) * 65 + rr] = (u16)v[j];
    }
    __syncthreads();
    const int n = t >> 3, kc = (t & 7) * 8;
    for (int nn = n; nn < 64; nn += 32) {
        s16x8 v;
#pragma unroll
        for (int j = 0; j < 8; j++) v[j] = (short)T[nn * 65 + kc + j];
        *(s16x8*)&WT[(size_t)(n0 + nn) * 768 + k0 + kc] = v;
    }
}

// ---------------------------------------------------------------------------
// Shared GEMM body: C[128 x 64] tile = A[128 x 768] @ W[768 x 64(head)] + bias
// ---------------------------------------------------------------------------
__device__ __forceinline__ void gemm_body(
    const void* __restrict__ A, int a_isf32, const u16* __restrict__ WT,
    const void* __restrict__ bias, int b_isf32, void* __restrict__ out,
    int out_isf32, int epi, int head, int m0)
{
    __shared__ __align__(16) u16 As[128 * 72];
    __shared__ __align__(16) u16 Bs[64 * 72];
    const int t = threadIdx.x;
    const int lane = t & 63, wave = t >> 6;
    const int quad = lane >> 4, l16 = lane & 15;
    const int mrow_base = (wave >> 1) * 64;   // wave's 64-row half
    const int ncol_base = (wave & 1) * 32;    // wave's 32-col half
    const int hbase = head * 64;

    f32x4 acc[4][2];
#pragma unroll
    for (int mt = 0; mt < 4; mt++)
#pragma unroll
        for (int nt = 0; nt < 2; nt++) acc[mt][nt] = (f32x4){0.f, 0.f, 0.f, 0.f};

    for (int k0 = 0; k0 < 768; k0 += 64) {
#pragma unroll
        for (int i = 0; i < 4; i++) {
            int seg = t + 256 * i;
            int r = seg >> 3, c = (seg & 7) * 8;
            *(s16x8*)&As[r * 72 + c] = load8b(A, (size_t)(m0 + r) * 768 + k0 + c, a_isf32);
        }
#pragma unroll
        for (int i = 0; i < 2; i++) {
            int seg = t + 256 * i;
            int r = seg >> 3, c = (seg & 7) * 8;
            *(s16x8*)&Bs[r * 72 + c] = *(const s16x8*)&WT[(size_t)(hbase + r) * 768 + k0 + c];
        }
        __syncthreads();
#pragma unroll
        for (int ks = 0; ks < 2; ks++) {
            s16x8 af[4], bf[2];
#pragma unroll
            for (int mt = 0; mt < 4; mt++)
                af[mt] = *(const s16x8*)&As[(mrow_base + mt * 16 + l16) * 72 + ks * 32 + quad * 8];
#pragma unroll
            for (int nt = 0; nt < 2; nt++)
                bf[nt] = *(const s16x8*)&Bs[(ncol_base + nt * 16 + l16) * 72 + ks * 32 + quad * 8];
#pragma unroll
            for (int mt = 0; mt < 4; mt++)
#pragma unroll
                for (int nt = 0; nt < 2; nt++)
                    acc[mt][nt] = MFMA16(af[mt], bf[nt], acc[mt][nt]);
        }
        __syncthreads();
    }

    if (epi == 2) {
#pragma unroll
        for (int mt = 0; mt < 4; mt++)
#pragma unroll
            for (int nt = 0; nt < 2; nt++) {
                int nc = ncol_base + nt * 16 + l16;
                float bvv = loadsc(bias, hbase + nc, b_isf32);
#pragma unroll
                for (int r = 0; r < 4; r++) {
                    int m = m0 + mrow_base + mt * 16 + quad * 4 + r;
                    float val = acc[mt][nt][r] + bvv;
                    size_t idx = (size_t)m * 768 + hbase + nc;
                    if (out_isf32) ((float*)out)[idx] = val;
                    else           ((u16*)out)[idx] = f2b(val);
                }
            }
    } else if (epi == 0) {
        u16* ob = (u16*)out;
#pragma unroll
        for (int mt = 0; mt < 4; mt++)
#pragma unroll
            for (int nt = 0; nt < 2; nt++) {
                int nc = ncol_base + nt * 16 + l16;
                float bvv = loadsc(bias, hbase + nc, b_isf32);
#pragma unroll
                for (int r = 0; r < 4; r++) {
                    int m = m0 + mrow_base + mt * 16 + quad * 4 + r;
                    int bidx = m >> 11, s = m & 2047;
                    ob[(((size_t)bidx * 12 + head) * 2048 + s) * 64 + nc] =
                        f2b(acc[mt][nt][r] + bvv);
                }
            }
    } else {
        // V: transpose the 128(s) x 64(dv) tile through LDS, write [dv][s]
        u16* ob = (u16*)out;
        u16* Ts = As;  // reuse (final loop __syncthreads already passed)
#pragma unroll
        for (int mt = 0; mt < 4; mt++)
#pragma unroll
            for (int nt = 0; nt < 2; nt++) {
                int nc = ncol_base + nt * 16 + l16;
                float bvv = loadsc(bias, hbase + nc, b_isf32);
#pragma unroll
                for (int r = 0; r < 4; r++) {
                    int ml = mrow_base + mt * 16 + quad * 4 + r;
                    Ts[nc * 136 + ml] = f2b(acc[mt][nt][r] + bvv);
                }
            }
        __syncthreads();
        const int bidx = m0 >> 11, sbase = m0 & 2047;
#pragma unroll
        for (int i = 0; i < 4; i++) {
            int seg = t + 256 * i;
            int dv = seg >> 4, scc = (seg & 15) * 8;
            s16x8 vv = *(const s16x8*)&Ts[dv * 136 + scc];
            *(s16x8*)&ob[(((size_t)bidx * 12 + head) * 64 + dv) * 2048 + sbase + scc] = vv;
        }
    }
}

__global__ __launch_bounds__(256) void k_qkv(
    const void* __restrict__ q, const void* __restrict__ k, const void* __restrict__ v,
    const u16* __restrict__ wt,
    const void* __restrict__ bq, const void* __restrict__ bk, const void* __restrict__ bv,
    u16* __restrict__ Q, u16* __restrict__ K, u16* __restrict__ Vt,
    const int* __restrict__ flag)
{
    const int isf32 = *flag;
    const int z = blockIdx.z;
    const void* A = (z == 0) ? q : (z == 1) ? k : v;
    const u16* WTz = wt + (size_t)z * 589824;
    const void* bias = (z == 0) ? bq : (z == 1) ? bk : bv;
    u16* out = (z == 0) ? Q : (z == 1) ? K : Vt;
    gemm_body(A, isf32, WTz, bias, isf32, out, 0, (z == 2) ? 1 : 0, blockIdx.y, blockIdx.x * 128);
}

__global__ __launch_bounds__(256) void k_oproj(
    const u16* __restrict__ ctx, const u16* __restrict__ wto,
    const void* __restrict__ bo, void* __restrict__ out,
    const int* __restrict__ flag)
{
    const int isf32 = *flag;
    gemm_body(ctx, 0, wto, bo, isf32, out, isf32, 2, blockIdx.y, blockIdx.x * 128);
}

// ---------------------------------------------------------------------------
// Attention: one block = 16 query rows of one (b, h). 512 threads (8 waves)
// so that 2 blocks/CU (64KB LDS) = 16 waves/CU for latency hiding.
// Phase 1: S = Q K^T * scale + mask (MFMA; mask load overlaps MFMA),
//          per-wave row-max tracked in registers -> wmax[16][8]
// Scan B : e = exp(s - mx) stored bf16 in place, row sum   (single exp pass)
// Scan C : p = e * inv -> LDS (bf16) + global attn (non-temporal)
// Phase 2: ctx = P @ V, split-K over 2 wave-groups + LDS partial reduce.
// Swizzle slot = (unit+row)&7: 16 rows -> 8 slots => phase-2 reads ~2-way.
// ---------------------------------------------------------------------------
__device__ __forceinline__ int sw_off(int row, int col) {
    int unit = col >> 3;
    int slot = (unit + row) & 7;
    return row * 2048 + (((unit & ~7) | slot) << 3) + (col & 7);
}

__global__ __launch_bounds__(512, 4) void k_attn(
    const u16* __restrict__ Q, const u16* __restrict__ K,
    const u16* __restrict__ Vt, const void* __restrict__ mask,
    void* __restrict__ outbase, u16* __restrict__ ctx,
    const int* __restrict__ flag)
{
    __shared__ __align__(16) u16 sc[16 * 2048];   // 64 KB scores/P
    __shared__ __align__(16) float part[1024];    // 4 KB split-K partials
    __shared__ float wmax[16][8];                 // per-wave row maxes
    const int isf32 = *flag;
    const int t = threadIdx.x;
    const int lane = t & 63, wave = t >> 6;
    const int quad = lane >> 4, l16 = lane & 15;
    const int q0 = blockIdx.x * 16;
    const int h = blockIdx.y, b = blockIdx.z;
    const int bh = b * 12 + h;

    const u16* Qb = Q + ((size_t)bh * 2048 + q0) * 64;
    const s16x8 qf0 = *(const s16x8*)&Qb[l16 * 64 + quad * 8];
    const s16x8 qf1 = *(const s16x8*)&Qb[l16 * 64 + 32 + quad * 8];

    const u16* Kb = K + (size_t)bh * 2048 * 64;
    const size_t mrow0 = ((size_t)bh * 2048 + q0) * 2048;

    // ---- Phase 1: scores + mask + per-lane row max ----
    float rm[4] = {-3.4e38f, -3.4e38f, -3.4e38f, -3.4e38f};
#pragma unroll 4
    for (int it = 0; it < 16; it++) {
        const int kc = it * 128 + wave * 16;
        const u16* kp = &Kb[(size_t)(kc + l16) * 64 + quad * 8];
        s16x8 kf0 = *(const s16x8*)kp;
        s16x8 kf1 = *(const s16x8*)(kp + 32);
        f32x4 a = (f32x4){0.f, 0.f, 0.f, 0.f};
        a = MFMA16(qf0, kf0, a);
        a = MFMA16(qf1, kf1, a);
        const int col = kc + l16;
#pragma unroll
        for (int r = 0; r < 4; r++) {
            const int row = quad * 4 + r;
            float m = loadsc_nt(mask, mrow0 + (size_t)row * 2048 + col, isf32);
            float x = a[r] * 0.125f + m;
            sc[sw_off(row, col)] = f2b(x);
            rm[r] = fmaxf(rm[r], x);
        }
    }
#pragma unroll
    for (int off = 8; off > 0; off >>= 1)
#pragma unroll
        for (int r = 0; r < 4; r++) rm[r] = fmaxf(rm[r], __shfl_xor(rm[r], off));
    if (l16 == 0) {
#pragma unroll
        for (int r = 0; r < 4; r++) wmax[quad * 4 + r][wave] = rm[r];
    }
    __syncthreads();

    // ---- Scans: 32 threads per row, 8-elem chunks ----
    const int row = t >> 5, j32 = t & 31;
    float mx = wmax[row][0];
#pragma unroll
    for (int w = 1; w < 8; w++) mx = fmaxf(mx, wmax[row][w]);

    float sum = 0.f;
#pragma unroll 4
    for (int i = 0; i < 8; i++) {
        const int c0 = j32 * 8 + i * 256;
        s16x8* sp = (s16x8*)&sc[sw_off(row, c0)];
        s16x8 sv = *sp, nv;
#pragma unroll
        for (int j = 0; j < 8; j++) {
            float e = __expf(b2f((u16)sv[j]) - mx);
            nv[j] = (short)f2b(e);
            sum += e;
        }
        *sp = nv;
    }
#pragma unroll
    for (int off = 16; off > 0; off >>= 1) sum += __shfl_xor(sum, off);
    const float inv = 1.0f / sum;

    // attn output: element offset 3145728 past `out`, dtype per flag
    const size_t aoff = 3145728 + mrow0 + (size_t)row * 2048;
#pragma unroll 2
    for (int i = 0; i < 8; i++) {
        const int c0 = j32 * 8 + i * 256;
        s16x8* sp = (s16x8*)&sc[sw_off(row, c0)];
        s16x8 sv = *sp, pv;
        float p[8];
#pragma unroll
        for (int j = 0; j < 8; j++) {
            p[j] = b2f((u16)sv[j]) * inv;
            pv[j] = (short)f2b(p[j]);
        }
        *sp = pv;
        if (isf32) {
            float* arow = (float*)outbase + aoff;
            f32x4 lo = (f32x4){p[0], p[1], p[2], p[3]};
            f32x4 hi = (f32x4){p[4], p[5], p[6], p[7]};
            __builtin_nontemporal_store(lo, (f32x4*)&arow[c0]);
            __builtin_nontemporal_store(hi, (f32x4*)&arow[c0 + 4]);
        } else {
            u16* arow = (u16*)outbase + aoff;
            __builtin_nontemporal_store(pv, (s16x8*)&arow[c0]);
        }
    }
    __syncthreads();

    // ---- Phase 2: ctx = P @ V, split-K over wave groups ----
    const int wg = wave >> 2;                 // 0: kk 0..31, 1: kk 32..63
    const int dv = (wave & 3) * 16 + l16;
    const u16* vrow = Vt + ((size_t)bh * 64 + dv) * 2048;
    f32x4 o = (f32x4){0.f, 0.f, 0.f, 0.f};
    const int kbase = wg * 32;
#pragma unroll 4
    for (int kk = 0; kk < 32; kk++) {
        const int kcol = (kbase + kk) * 32 + quad * 8;
        s16x8 pa = *(const s16x8*)&sc[sw_off(l16, kcol)];
        s16x8 vb = *(const s16x8*)&vrow[kcol];
        o = MFMA16(pa, vb, o);
    }
    if (wg == 1) *(f32x4*)&part[((wave & 3) * 64 + lane) * 4] = o;
    __syncthreads();
    if (wg == 0) {
        f32x4 o2 = *(const f32x4*)&part[((wave & 3) * 64 + lane) * 4];
#pragma unroll
        for (int r = 0; r < 4; r++)
            ctx[((size_t)b * 2048 + q0 + quad * 4 + r) * 768 + h * 64 + dv] =
                f2b(o[r] + o2[r]);
    }
}

// ---------------------------------------------------------------------------
extern "C" void kernel_launch(void* const* d_in, const int* in_sizes, int n_in,
                              void* d_out, int out_size, void* d_ws, size_t ws_size,
                              hipStream_t stream) {
    const void* q    = d_in[0];
    const void* k    = d_in[1];
    const void* v    = d_in[2];
    const void* mask = d_in[3];
    const void* Wq   = d_in[4];
    const void* bq   = d_in[5];
    const void* Wk   = d_in[6];
    const void* bk   = d_in[7];
    const void* Wv   = d_in[8];
    const void* bv   = d_in[9];
    const void* Wo   = d_in[10];
    const void* bo   = d_in[11];

    u16* ws  = (u16*)d_ws;
    u16* WT  = ws;                       // 4 x 589824  (WqT,WkT,WvT,WoT)
    u16* Qb  = ws + 2359296;             // [2,12,2048,64]
    u16* Kb  = ws + 5505024;             // [2,12,2048,64]
    u16* Vtb = ws + 8650752;             // [2,12,64,2048]
    u16* ctx = ws + 11796480;            // [2,2048,768]
    int* flag = (int*)(ws + 14942208);   // dtype flag (1 => fp32 tensors)

    k_detect<<<1, 64, 0, stream>>>((const u16*)q, flag);
    k_transpose<<<dim3(12, 12, 4), 256, 0, stream>>>(Wq, Wk, Wv, Wo, WT, flag);
    k_qkv<<<dim3(32, 12, 3), 256, 0, stream>>>(q, k, v, WT, bq, bk, bv, Qb, Kb, Vtb, flag);
    k_attn<<<dim3(128, 12, 2), 512, 0, stream>>>(Qb, Kb, Vtb, mask, d_out, ctx, flag);
    k_oproj<<<dim3(32, 12, 1), 256, 0, stream>>>(ctx, WT + 3 * 589824, bo, d_out, flag);
}

// Round 3
// 924.274 us; speedup vs baseline: 1.0910x; 1.0910x over previous
//
#include <hip/hip_runtime.h>
#include <hip/hip_bf16.h>

typedef unsigned short u16;
typedef __attribute__((ext_vector_type(8))) short s16x8;
typedef __attribute__((ext_vector_type(4))) float f32x4;

#define MFMA16(a, b, c) __builtin_amdgcn_mfma_f32_16x16x32_bf16((a), (b), (c), 0, 0, 0)

__device__ __forceinline__ float b2f(u16 u) {
    union { float f; unsigned int i; } c; c.i = ((unsigned int)u) << 16; return c.f;
}
__device__ __forceinline__ u16 f2b(float f) {
    union { float f; unsigned int i; } c; c.f = f;
    unsigned int i = c.i;
    return (u16)((i + 0x7fffu + ((i >> 16) & 1u)) >> 16);  // RNE
}

// Load 8 consecutive elements of an EXTERNAL tensor (runtime dtype) as bf16.
__device__ __forceinline__ s16x8 load8b(const void* base, size_t idx, int isf32) {
    if (!isf32) {
        return *(const s16x8*)((const u16*)base + idx);
    } else {
        const float* p = (const float*)base + idx;
        f32x4 a = *(const f32x4*)p;
        f32x4 b = *(const f32x4*)(p + 4);
        s16x8 v;
        v[0] = (short)f2b(a[0]); v[1] = (short)f2b(a[1]);
        v[2] = (short)f2b(a[2]); v[3] = (short)f2b(a[3]);
        v[4] = (short)f2b(b[0]); v[5] = (short)f2b(b[1]);
        v[6] = (short)f2b(b[2]); v[7] = (short)f2b(b[3]);
        return v;
    }
}
__device__ __forceinline__ float loadsc(const void* base, size_t idx, int isf32) {
    return isf32 ? ((const float*)base)[idx] : b2f(((const u16*)base)[idx]);
}
// Vectorized non-temporal 8-elem load (streaming read-once data: the mask).
__device__ __forceinline__ void load8f_nt(const void* base, size_t idx, int isf32, float* o) {
    if (!isf32) {
        s16x8 m = __builtin_nontemporal_load((const s16x8*)((const u16*)base + idx));
#pragma unroll
        for (int j = 0; j < 8; j++) o[j] = b2f((u16)m[j]);
    } else {
        const float* p = (const float*)base + idx;
        f32x4 a = __builtin_nontemporal_load((const f32x4*)p);
        f32x4 b = __builtin_nontemporal_load((const f32x4*)(p + 4));
        o[0] = a[0]; o[1] = a[1]; o[2] = a[2]; o[3] = a[3];
        o[4] = b[0]; o[5] = b[1]; o[6] = b[2]; o[7] = b[3];
    }
}

// ---------------------------------------------------------------------------
// Dtype detection: read q's first 1024 u16 words as bf16. Real-bf16 N(0,1)
// data has exponent in [110,135] essentially always; fp32 data read as u16
// halves gives ~55% sane words. Flag drives BOTH input and output dtype.
// ---------------------------------------------------------------------------
__global__ __launch_bounds__(64) void k_detect(const u16* __restrict__ q, int* __restrict__ flag) {
    int t = threadIdx.x;
    int cnt = 0;
#pragma unroll
    for (int i = 0; i < 16; i++) {
        u16 u = q[t * 16 + i];
        int e = (u >> 7) & 0xFF;
        cnt += (e >= 110 && e <= 135) ? 1 : 0;
    }
#pragma unroll
    for (int off = 32; off > 0; off >>= 1) cnt += __shfl_down(cnt, off);
    if (t == 0) *flag = (cnt < 850) ? 1 : 0;  // 1 => fp32 tensors
}

// ---------------------------------------------------------------------------
// Transpose the 4 weight matrices (768x768) to WT[n][k] (k-contig) in bf16.
// ---------------------------------------------------------------------------
__global__ __launch_bounds__(256) void k_transpose(
    const void* __restrict__ w0, const void* __restrict__ w1,
    const void* __restrict__ w2, const void* __restrict__ w3,
    u16* __restrict__ wt, const int* __restrict__ flag)
{
    __shared__ __align__(16) u16 T[64 * 65];
    const int isf32 = *flag;
    const int z = blockIdx.z;
    const void* W = (z == 0) ? w0 : (z == 1) ? w1 : (z == 2) ? w2 : w3;
    u16* WT = wt + (size_t)z * 589824;
    const int n0 = blockIdx.x * 64, k0 = blockIdx.y * 64;
    const int t = threadIdx.x;
    const int r = t >> 3, c = (t & 7) * 8;
    for (int rr = r; rr < 64; rr += 32) {
        s16x8 v = load8b(W, (size_t)(k0 + rr) * 768 + n0 + c, isf32);
#pragma unroll
        for (int j = 0; j < 8; j++) T[(c + j) * 65 + rr] = (u16)v[j];
    }
    __syncthreads();
    const int n = t >> 3, kc = (t & 7) * 8;
    for (int nn = n; nn < 64; nn += 32) {
        s16x8 v;
#pragma unroll
        for (int j = 0; j < 8; j++) v[j] = (short)T[nn * 65 + kc + j];
        *(s16x8*)&WT[(size_t)(n0 + nn) * 768 + k0 + kc] = v;
    }
}

// ---------------------------------------------------------------------------
// Shared GEMM body: C[128 x 64] tile = A[128 x 768] @ W[768 x 64(head)] + bias
// ---------------------------------------------------------------------------
__device__ __forceinline__ void gemm_body(
    const void* __restrict__ A, int a_isf32, const u16* __restrict__ WT,
    const void* __restrict__ bias, int b_isf32, void* __restrict__ out,
    int out_isf32, int epi, int head, int m0)
{
    __shared__ __align__(16) u16 As[128 * 72];
    __shared__ __align__(16) u16 Bs[64 * 72];
    const int t = threadIdx.x;
    const int lane = t & 63, wave = t >> 6;
    const int quad = lane >> 4, l16 = lane & 15;
    const int mrow_base = (wave >> 1) * 64;   // wave's 64-row half
    const int ncol_base = (wave & 1) * 32;    // wave's 32-col half
    const int hbase = head * 64;

    f32x4 acc[4][2];
#pragma unroll
    for (int mt = 0; mt < 4; mt++)
#pragma unroll
        for (int nt = 0; nt < 2; nt++) acc[mt][nt] = (f32x4){0.f, 0.f, 0.f, 0.f};

    for (int k0 = 0; k0 < 768; k0 += 64) {
#pragma unroll
        for (int i = 0; i < 4; i++) {
            int seg = t + 256 * i;
            int r = seg >> 3, c = (seg & 7) * 8;
            *(s16x8*)&As[r * 72 + c] = load8b(A, (size_t)(m0 + r) * 768 + k0 + c, a_isf32);
        }
#pragma unroll
        for (int i = 0; i < 2; i++) {
            int seg = t + 256 * i;
            int r = seg >> 3, c = (seg & 7) * 8;
            *(s16x8*)&Bs[r * 72 + c] = *(const s16x8*)&WT[(size_t)(hbase + r) * 768 + k0 + c];
        }
        __syncthreads();
#pragma unroll
        for (int ks = 0; ks < 2; ks++) {
            s16x8 af[4], bf[2];
#pragma unroll
            for (int mt = 0; mt < 4; mt++)
                af[mt] = *(const s16x8*)&As[(mrow_base + mt * 16 + l16) * 72 + ks * 32 + quad * 8];
#pragma unroll
            for (int nt = 0; nt < 2; nt++)
                bf[nt] = *(const s16x8*)&Bs[(ncol_base + nt * 16 + l16) * 72 + ks * 32 + quad * 8];
#pragma unroll
            for (int mt = 0; mt < 4; mt++)
#pragma unroll
                for (int nt = 0; nt < 2; nt++)
                    acc[mt][nt] = MFMA16(af[mt], bf[nt], acc[mt][nt]);
        }
        __syncthreads();
    }

    if (epi == 2) {
#pragma unroll
        for (int mt = 0; mt < 4; mt++)
#pragma unroll
            for (int nt = 0; nt < 2; nt++) {
                int nc = ncol_base + nt * 16 + l16;
                float bvv = loadsc(bias, hbase + nc, b_isf32);
#pragma unroll
                for (int r = 0; r < 4; r++) {
                    int m = m0 + mrow_base + mt * 16 + quad * 4 + r;
                    float val = acc[mt][nt][r] + bvv;
                    size_t idx = (size_t)m * 768 + hbase + nc;
                    if (out_isf32) ((float*)out)[idx] = val;
                    else           ((u16*)out)[idx] = f2b(val);
                }
            }
    } else if (epi == 0) {
        u16* ob = (u16*)out;
#pragma unroll
        for (int mt = 0; mt < 4; mt++)
#pragma unroll
            for (int nt = 0; nt < 2; nt++) {
                int nc = ncol_base + nt * 16 + l16;
                float bvv = loadsc(bias, hbase + nc, b_isf32);
#pragma unroll
                for (int r = 0; r < 4; r++) {
                    int m = m0 + mrow_base + mt * 16 + quad * 4 + r;
                    int bidx = m >> 11, s = m & 2047;
                    ob[(((size_t)bidx * 12 + head) * 2048 + s) * 64 + nc] =
                        f2b(acc[mt][nt][r] + bvv);
                }
            }
    } else {
        // V: transpose the 128(s) x 64(dv) tile through LDS, write [dv][s]
        u16* ob = (u16*)out;
        u16* Ts = As;  // reuse (final loop __syncthreads already passed)
#pragma unroll
        for (int mt = 0; mt < 4; mt++)
#pragma unroll
            for (int nt = 0; nt < 2; nt++) {
                int nc = ncol_base + nt * 16 + l16;
                float bvv = loadsc(bias, hbase + nc, b_isf32);
#pragma unroll
                for (int r = 0; r < 4; r++) {
                    int ml = mrow_base + mt * 16 + quad * 4 + r;
                    Ts[nc * 136 + ml] = f2b(acc[mt][nt][r] + bvv);
                }
            }
        __syncthreads();
        const int bidx = m0 >> 11, sbase = m0 & 2047;
#pragma unroll
        for (int i = 0; i < 4; i++) {
            int seg = t + 256 * i;
            int dv = seg >> 4, scc = (seg & 15) * 8;
            s16x8 vv = *(const s16x8*)&Ts[dv * 136 + scc];
            *(s16x8*)&ob[(((size_t)bidx * 12 + head) * 64 + dv) * 2048 + sbase + scc] = vv;
        }
    }
}

__global__ __launch_bounds__(256) void k_qkv(
    const void* __restrict__ q, const void* __restrict__ k, const void* __restrict__ v,
    const u16* __restrict__ wt,
    const void* __restrict__ bq, const void* __restrict__ bk, const void* __restrict__ bv,
    u16* __restrict__ Q, u16* __restrict__ K, u16* __restrict__ Vt,
    const int* __restrict__ flag)
{
    const int isf32 = *flag;
    const int z = blockIdx.z;
    const void* A = (z == 0) ? q : (z == 1) ? k : v;
    const u16* WTz = wt + (size_t)z * 589824;
    const void* bias = (z == 0) ? bq : (z == 1) ? bk : bv;
    u16* out = (z == 0) ? Q : (z == 1) ? K : Vt;
    gemm_body(A, isf32, WTz, bias, isf32, out, 0, (z == 2) ? 1 : 0, blockIdx.y, blockIdx.x * 128);
}

__global__ __launch_bounds__(256) void k_oproj(
    const u16* __restrict__ ctx, const u16* __restrict__ wto,
    const void* __restrict__ bo, void* __restrict__ out,
    const int* __restrict__ flag)
{
    const int isf32 = *flag;
    gemm_body(ctx, 0, wto, bo, isf32, out, isf32, 2, blockIdx.y, blockIdx.x * 128);
}

// ---------------------------------------------------------------------------
// Attention: one block = 16 query rows of one (b, h). 512 threads (8 waves),
// 2 blocks/CU (64KB LDS) = 16 waves/CU.
// Phase 1: S = Q K^T * scale (MFMA) -> LDS bf16 (swizzled)
// Scan A : += mask (VECTORIZED 8-elem NT loads, 32 thr/row) + row max (shuffle)
// Scan B : e = exp(s-mx) -> LDS (in place), row sum (shuffle), invs[row] saved
// Scan C : global attn store p = e*inv (plain stores; NT stores cost +46MB)
// Phase 2: ctx = (e @ V) * inv, split-K over 2 wave-groups + LDS reduce.
// All row reductions stay inside one wave (32 thr/row) -> shuffle-only.
// ---------------------------------------------------------------------------
__device__ __forceinline__ int sw_off(int row, int col) {
    int unit = col >> 3;
    int slot = (unit + row) & 7;
    return row * 2048 + (((unit & ~7) | slot) << 3) + (col & 7);
}

__global__ __launch_bounds__(512, 4) void k_attn(
    const u16* __restrict__ Q, const u16* __restrict__ K,
    const u16* __restrict__ Vt, const void* __restrict__ mask,
    void* __restrict__ outbase, u16* __restrict__ ctx,
    const int* __restrict__ flag)
{
    __shared__ __align__(16) u16 sc[16 * 2048];   // 64 KB scores/e
    __shared__ __align__(16) float part[1024];    // 4 KB split-K partials
    __shared__ float invs[16];                    // per-row 1/sum
    const int isf32 = *flag;
    const int t = threadIdx.x;
    const int lane = t & 63, wave = t >> 6;
    const int quad = lane >> 4, l16 = lane & 15;
    const int q0 = blockIdx.x * 16;
    const int h = blockIdx.y, b = blockIdx.z;
    const int bh = b * 12 + h;

    const u16* Qb = Q + ((size_t)bh * 2048 + q0) * 64;
    const s16x8 qf0 = *(const s16x8*)&Qb[l16 * 64 + quad * 8];
    const s16x8 qf1 = *(const s16x8*)&Qb[l16 * 64 + 32 + quad * 8];

    const u16* Kb = K + (size_t)bh * 2048 * 64;
    const size_t mrow0 = ((size_t)bh * 2048 + q0) * 2048;

    // ---- Phase 1: scores -> LDS ----
#pragma unroll 4
    for (int it = 0; it < 16; it++) {
        const int kc = it * 128 + wave * 16;
        const u16* kp = &Kb[(size_t)(kc + l16) * 64 + quad * 8];
        s16x8 kf0 = *(const s16x8*)kp;
        s16x8 kf1 = *(const s16x8*)(kp + 32);
        f32x4 a = (f32x4){0.f, 0.f, 0.f, 0.f};
        a = MFMA16(qf0, kf0, a);
        a = MFMA16(qf1, kf1, a);
        const int col = kc + l16;
#pragma unroll
        for (int r = 0; r < 4; r++)
            sc[sw_off(quad * 4 + r, col)] = f2b(a[r] * 0.125f);
    }
    __syncthreads();

    // ---- Scan A: mask add (vectorized) + row max ----
    const int row = t >> 5, j32 = t & 31;
    float mx = -3.4e38f;
#pragma unroll 4
    for (int i = 0; i < 8; i++) {
        const int c0 = j32 * 8 + i * 256;
        float mk[8];
        load8f_nt(mask, mrow0 + (size_t)row * 2048 + c0, isf32, mk);
        s16x8* sp = (s16x8*)&sc[sw_off(row, c0)];
        s16x8 sv = *sp, nv;
#pragma unroll
        for (int j = 0; j < 8; j++) {
            float x = b2f((u16)sv[j]) + mk[j];
            nv[j] = (short)f2b(x);
            mx = fmaxf(mx, x);
        }
        *sp = nv;
    }
#pragma unroll
    for (int off = 16; off > 0; off >>= 1) mx = fmaxf(mx, __shfl_xor(mx, off));

    // ---- Scan B: e = exp(x - mx), row sum ----
    float sum = 0.f;
#pragma unroll 4
    for (int i = 0; i < 8; i++) {
        const int c0 = j32 * 8 + i * 256;
        s16x8* sp = (s16x8*)&sc[sw_off(row, c0)];
        s16x8 sv = *sp, nv;
#pragma unroll
        for (int j = 0; j < 8; j++) {
            float e = __expf(b2f((u16)sv[j]) - mx);
            nv[j] = (short)f2b(e);
            sum += e;
        }
        *sp = nv;
    }
#pragma unroll
    for (int off = 16; off > 0; off >>= 1) sum += __shfl_xor(sum, off);
    const float inv = 1.0f / sum;
    if (j32 == 0) invs[row] = inv;

    // ---- Scan C: global attn store (plain stores) ----
    const size_t aoff = 3145728 + mrow0 + (size_t)row * 2048;
#pragma unroll 2
    for (int i = 0; i < 8; i++) {
        const int c0 = j32 * 8 + i * 256;
        s16x8 sv = *(const s16x8*)&sc[sw_off(row, c0)];
        if (isf32) {
            float* arow = (float*)outbase + aoff;
            f32x4 lo, hi;
#pragma unroll
            for (int j = 0; j < 4; j++) lo[j] = b2f((u16)sv[j]) * inv;
#pragma unroll
            for (int j = 0; j < 4; j++) hi[j] = b2f((u16)sv[j + 4]) * inv;
            *(f32x4*)&arow[c0] = lo;
            *(f32x4*)&arow[c0 + 4] = hi;
        } else {
            u16* arow = (u16*)outbase + aoff;
            s16x8 pv;
#pragma unroll
            for (int j = 0; j < 8; j++) pv[j] = (short)f2b(b2f((u16)sv[j]) * inv);
            *(s16x8*)&arow[c0] = pv;
        }
    }
    __syncthreads();

    // ---- Phase 2: ctx = (e @ V) * inv, split-K over wave groups ----
    const int wg = wave >> 2;                 // 0: kk 0..31, 1: kk 32..63
    const int dv = (wave & 3) * 16 + l16;
    const u16* vrow = Vt + ((size_t)bh * 64 + dv) * 2048;
    f32x4 o = (f32x4){0.f, 0.f, 0.f, 0.f};
    const int kbase = wg * 32;
#pragma unroll 4
    for (int kk = 0; kk < 32; kk++) {
        const int kcol = (kbase + kk) * 32 + quad * 8;
        s16x8 pa = *(const s16x8*)&sc[sw_off(l16, kcol)];
        s16x8 vb = *(const s16x8*)&vrow[kcol];
        o = MFMA16(pa, vb, o);
    }
    if (wg == 1) *(f32x4*)&part[((wave & 3) * 64 + lane) * 4] = o;
    __syncthreads();
    if (wg == 0) {
        f32x4 o2 = *(const f32x4*)&part[((wave & 3) * 64 + lane) * 4];
#pragma unroll
        for (int r = 0; r < 4; r++) {
            float val = (o[r] + o2[r]) * invs[quad * 4 + r];
            ctx[((size_t)b * 2048 + q0 + quad * 4 + r) * 768 + h * 64 + dv] = f2b(val);
        }
    }
}

// ---------------------------------------------------------------------------
extern "C" void kernel_launch(void* const* d_in, const int* in_sizes, int n_in,
                              void* d_out, int out_size, void* d_ws, size_t ws_size,
                              hipStream_t stream) {
    const void* q    = d_in[0];
    const void* k    = d_in[1];
    const void* v    = d_in[2];
    const void* mask = d_in[3];
    const void* Wq   = d_in[4];
    const void* bq   = d_in[5];
    const void* Wk   = d_in[6];
    const void* bk   = d_in[7];
    const void* Wv   = d_in[8];
    const void* bv   = d_in[9];
    const void* Wo   = d_in[10];
    const void* bo   = d_in[11];

    u16* ws  = (u16*)d_ws;
    u16* WT  = ws;                       // 4 x 589824  (WqT,WkT,WvT,WoT)
    u16* Qb  = ws + 2359296;             // [2,12,2048,64]
    u16* Kb  = ws + 5505024;             // [2,12,2048,64]
    u16* Vtb = ws + 8650752;             // [2,12,64,2048]
    u16* ctx = ws + 11796480;            // [2,2048,768]
    int* flag = (int*)(ws + 14942208);   // dtype flag (1 => fp32 tensors)

    k_detect<<<1, 64, 0, stream>>>((const u16*)q, flag);
    k_transpose<<<dim3(12, 12, 4), 256, 0, stream>>>(Wq, Wk, Wv, Wo, WT, flag);
    k_qkv<<<dim3(32, 12, 3), 256, 0, stream>>>(q, k, v, WT, bq, bk, bv, Qb, Kb, Vtb, flag);
    k_attn<<<dim3(128, 12, 2), 512, 0, stream>>>(Qb, Kb, Vtb, mask, d_out, ctx, flag);
    k_oproj<<<dim3(32, 12, 1), 256, 0, stream>>>(ctx, WT + 3 * 589824, bo, d_out, flag);
}

// Round 4
// 902.579 us; speedup vs baseline: 1.1173x; 1.0240x over previous
//
#include <hip/hip_runtime.h>
#include <hip/hip_bf16.h>

typedef unsigned short u16;
typedef __attribute__((ext_vector_type(8))) short s16x8;
typedef __attribute__((ext_vector_type(4))) float f32x4;

#define MFMA16(a, b, c) __builtin_amdgcn_mfma_f32_16x16x32_bf16((a), (b), (c), 0, 0, 0)

__device__ __forceinline__ float b2f(u16 u) {
    union { float f; unsigned int i; } c; c.i = ((unsigned int)u) << 16; return c.f;
}
__device__ __forceinline__ u16 f2b(float f) {
    union { float f; unsigned int i; } c; c.f = f;
    unsigned int i = c.i;
    return (u16)((i + 0x7fffu + ((i >> 16) & 1u)) >> 16);  // RNE
}

// Load 8 consecutive elements of an EXTERNAL tensor (runtime dtype) as bf16.
__device__ __forceinline__ s16x8 load8b(const void* base, size_t idx, int isf32) {
    if (!isf32) {
        return *(const s16x8*)((const u16*)base + idx);
    } else {
        const float* p = (const float*)base + idx;
        f32x4 a = *(const f32x4*)p;
        f32x4 b = *(const f32x4*)(p + 4);
        s16x8 v;
        v[0] = (short)f2b(a[0]); v[1] = (short)f2b(a[1]);
        v[2] = (short)f2b(a[2]); v[3] = (short)f2b(a[3]);
        v[4] = (short)f2b(b[0]); v[5] = (short)f2b(b[1]);
        v[6] = (short)f2b(b[2]); v[7] = (short)f2b(b[3]);
        return v;
    }
}
__device__ __forceinline__ float loadsc(const void* base, size_t idx, int isf32) {
    return isf32 ? ((const float*)base)[idx] : b2f(((const u16*)base)[idx]);
}
// Vectorized non-temporal 8-elem load (streaming read-once data: the mask).
__device__ __forceinline__ void load8f_nt(const void* base, size_t idx, int isf32, float* o) {
    if (!isf32) {
        s16x8 m = __builtin_nontemporal_load((const s16x8*)((const u16*)base + idx));
#pragma unroll
        for (int j = 0; j < 8; j++) o[j] = b2f((u16)m[j]);
    } else {
        const float* p = (const float*)base + idx;
        f32x4 a = __builtin_nontemporal_load((const f32x4*)p);
        f32x4 b = __builtin_nontemporal_load((const f32x4*)(p + 4));
        o[0] = a[0]; o[1] = a[1]; o[2] = a[2]; o[3] = a[3];
        o[4] = b[0]; o[5] = b[1]; o[6] = b[2]; o[7] = b[3];
    }
}

// ---------------------------------------------------------------------------
// Dtype detection: read q's first 1024 u16 words as bf16. Real-bf16 N(0,1)
// data has exponent in [110,135] essentially always; fp32 data read as u16
// halves gives ~55% sane words. Flag drives BOTH input and output dtype.
// ---------------------------------------------------------------------------
__global__ __launch_bounds__(64) void k_detect(const u16* __restrict__ q, int* __restrict__ flag) {
    int t = threadIdx.x;
    int cnt = 0;
#pragma unroll
    for (int i = 0; i < 16; i++) {
        u16 u = q[t * 16 + i];
        int e = (u >> 7) & 0xFF;
        cnt += (e >= 110 && e <= 135) ? 1 : 0;
    }
#pragma unroll
    for (int off = 32; off > 0; off >>= 1) cnt += __shfl_down(cnt, off);
    if (t == 0) *flag = (cnt < 850) ? 1 : 0;  // 1 => fp32 tensors
}

// ---------------------------------------------------------------------------
// Convert q/k/v to bf16 once (k_qkv then stages bf16: half the fetch bytes,
// no per-head redundant fp32->bf16 VALU). For bf16 inputs it's a plain copy.
// ---------------------------------------------------------------------------
__global__ __launch_bounds__(256) void k_cvt(
    const void* __restrict__ q, const void* __restrict__ k, const void* __restrict__ v,
    u16* __restrict__ Qc, u16* __restrict__ Kc, u16* __restrict__ Vc,
    const int* __restrict__ flag)
{
    const int isf32 = *flag;
    const int z = blockIdx.y;
    const void* src = (z == 0) ? q : (z == 1) ? k : v;
    u16* dst = (z == 0) ? Qc : (z == 1) ? Kc : Vc;
    size_t idx = ((size_t)blockIdx.x * 256 + threadIdx.x) * 8;
    s16x8 vv = load8b(src, idx, isf32);
    *(s16x8*)&dst[idx] = vv;
}

// ---------------------------------------------------------------------------
// Transpose the 4 weight matrices (768x768) to WT[n][k] (k-contig) in bf16.
// ---------------------------------------------------------------------------
__global__ __launch_bounds__(256) void k_transpose(
    const void* __restrict__ w0, const void* __restrict__ w1,
    const void* __restrict__ w2, const void* __restrict__ w3,
    u16* __restrict__ wt, const int* __restrict__ flag)
{
    __shared__ __align__(16) u16 T[64 * 65];
    const int isf32 = *flag;
    const int z = blockIdx.z;
    const void* W = (z == 0) ? w0 : (z == 1) ? w1 : (z == 2) ? w2 : w3;
    u16* WT = wt + (size_t)z * 589824;
    const int n0 = blockIdx.x * 64, k0 = blockIdx.y * 64;
    const int t = threadIdx.x;
    const int r = t >> 3, c = (t & 7) * 8;
    for (int rr = r; rr < 64; rr += 32) {
        s16x8 v = load8b(W, (size_t)(k0 + rr) * 768 + n0 + c, isf32);
#pragma unroll
        for (int j = 0; j < 8; j++) T[(c + j) * 65 + rr] = (u16)v[j];
    }
    __syncthreads();
    const int n = t >> 3, kc = (t & 7) * 8;
    for (int nn = n; nn < 64; nn += 32) {
        s16x8 v;
#pragma unroll
        for (int j = 0; j < 8; j++) v[j] = (short)T[nn * 65 + kc + j];
        *(s16x8*)&WT[(size_t)(n0 + nn) * 768 + k0 + kc] = v;
    }
}

// ---------------------------------------------------------------------------
// Shared GEMM body: C[128 x 64] tile = A[128 x 768] @ W[768 x 64(head)] + bias
// ---------------------------------------------------------------------------
__device__ __forceinline__ void gemm_body(
    const void* __restrict__ A, int a_isf32, const u16* __restrict__ WT,
    const void* __restrict__ bias, int b_isf32, void* __restrict__ out,
    int out_isf32, int epi, int head, int m0)
{
    __shared__ __align__(16) u16 As[128 * 72];
    __shared__ __align__(16) u16 Bs[64 * 72];
    const int t = threadIdx.x;
    const int lane = t & 63, wave = t >> 6;
    const int quad = lane >> 4, l16 = lane & 15;
    const int mrow_base = (wave >> 1) * 64;   // wave's 64-row half
    const int ncol_base = (wave & 1) * 32;    // wave's 32-col half
    const int hbase = head * 64;

    f32x4 acc[4][2];
#pragma unroll
    for (int mt = 0; mt < 4; mt++)
#pragma unroll
        for (int nt = 0; nt < 2; nt++) acc[mt][nt] = (f32x4){0.f, 0.f, 0.f, 0.f};

    for (int k0 = 0; k0 < 768; k0 += 64) {
#pragma unroll
        for (int i = 0; i < 4; i++) {
            int seg = t + 256 * i;
            int r = seg >> 3, c = (seg & 7) * 8;
            *(s16x8*)&As[r * 72 + c] = load8b(A, (size_t)(m0 + r) * 768 + k0 + c, a_isf32);
        }
#pragma unroll
        for (int i = 0; i < 2; i++) {
            int seg = t + 256 * i;
            int r = seg >> 3, c = (seg & 7) * 8;
            *(s16x8*)&Bs[r * 72 + c] = *(const s16x8*)&WT[(size_t)(hbase + r) * 768 + k0 + c];
        }
        __syncthreads();
#pragma unroll
        for (int ks = 0; ks < 2; ks++) {
            s16x8 af[4], bf[2];
#pragma unroll
            for (int mt = 0; mt < 4; mt++)
                af[mt] = *(const s16x8*)&As[(mrow_base + mt * 16 + l16) * 72 + ks * 32 + quad * 8];
#pragma unroll
            for (int nt = 0; nt < 2; nt++)
                bf[nt] = *(const s16x8*)&Bs[(ncol_base + nt * 16 + l16) * 72 + ks * 32 + quad * 8];
#pragma unroll
            for (int mt = 0; mt < 4; mt++)
#pragma unroll
                for (int nt = 0; nt < 2; nt++)
                    acc[mt][nt] = MFMA16(af[mt], bf[nt], acc[mt][nt]);
        }
        __syncthreads();
    }

    if (epi == 2) {
#pragma unroll
        for (int mt = 0; mt < 4; mt++)
#pragma unroll
            for (int nt = 0; nt < 2; nt++) {
                int nc = ncol_base + nt * 16 + l16;
                float bvv = loadsc(bias, hbase + nc, b_isf32);
#pragma unroll
                for (int r = 0; r < 4; r++) {
                    int m = m0 + mrow_base + mt * 16 + quad * 4 + r;
                    float val = acc[mt][nt][r] + bvv;
                    size_t idx = (size_t)m * 768 + hbase + nc;
                    if (out_isf32) ((float*)out)[idx] = val;
                    else           ((u16*)out)[idx] = f2b(val);
                }
            }
    } else if (epi == 0) {
        u16* ob = (u16*)out;
#pragma unroll
        for (int mt = 0; mt < 4; mt++)
#pragma unroll
            for (int nt = 0; nt < 2; nt++) {
                int nc = ncol_base + nt * 16 + l16;
                float bvv = loadsc(bias, hbase + nc, b_isf32);
#pragma unroll
                for (int r = 0; r < 4; r++) {
                    int m = m0 + mrow_base + mt * 16 + quad * 4 + r;
                    int bidx = m >> 11, s = m & 2047;
                    ob[(((size_t)bidx * 12 + head) * 2048 + s) * 64 + nc] =
                        f2b(acc[mt][nt][r] + bvv);
                }
            }
    } else {
        // V: transpose the 128(s) x 64(dv) tile through LDS, write [dv][s]
        u16* ob = (u16*)out;
        u16* Ts = As;  // reuse (final loop __syncthreads already passed)
#pragma unroll
        for (int mt = 0; mt < 4; mt++)
#pragma unroll
            for (int nt = 0; nt < 2; nt++) {
                int nc = ncol_base + nt * 16 + l16;
                float bvv = loadsc(bias, hbase + nc, b_isf32);
#pragma unroll
                for (int r = 0; r < 4; r++) {
                    int ml = mrow_base + mt * 16 + quad * 4 + r;
                    Ts[nc * 136 + ml] = f2b(acc[mt][nt][r] + bvv);
                }
            }
        __syncthreads();
        const int bidx = m0 >> 11, sbase = m0 & 2047;
#pragma unroll
        for (int i = 0; i < 4; i++) {
            int seg = t + 256 * i;
            int dv = seg >> 4, scc = (seg & 15) * 8;
            s16x8 vv = *(const s16x8*)&Ts[dv * 136 + scc];
            *(s16x8*)&ob[(((size_t)bidx * 12 + head) * 64 + dv) * 2048 + sbase + scc] = vv;
        }
    }
}

__global__ __launch_bounds__(256) void k_qkv(
    const void* __restrict__ q, const void* __restrict__ k, const void* __restrict__ v,
    const u16* __restrict__ wt,
    const void* __restrict__ bq, const void* __restrict__ bk, const void* __restrict__ bv,
    u16* __restrict__ Q, u16* __restrict__ K, u16* __restrict__ Vt,
    const int* __restrict__ flag, int use_cvt)
{
    const int isf32 = *flag;
    const int z = blockIdx.z;
    const void* A = (z == 0) ? q : (z == 1) ? k : v;
    const u16* WTz = wt + (size_t)z * 589824;
    const void* bias = (z == 0) ? bq : (z == 1) ? bk : bv;
    u16* out = (z == 0) ? Q : (z == 1) ? K : Vt;
    gemm_body(A, use_cvt ? 0 : isf32, WTz, bias, isf32, out, 0,
              (z == 2) ? 1 : 0, blockIdx.y, blockIdx.x * 128);
}

__global__ __launch_bounds__(256) void k_oproj(
    const u16* __restrict__ ctx, const u16* __restrict__ wto,
    const void* __restrict__ bo, void* __restrict__ out,
    const int* __restrict__ flag)
{
    const int isf32 = *flag;
    gemm_body(ctx, 0, wto, bo, isf32, out, isf32, 2, blockIdx.y, blockIdx.x * 128);
}

// ---------------------------------------------------------------------------
// Attention: one block = 16 query rows of one (b, h). 512 threads (8 waves),
// 2 blocks/CU (64KB LDS) = 16 waves/CU.
// Prefetch: mask row-chunks into 64 regs BEFORE phase 1 (HBM latency hides
//           under QK^T).
// Phase 1 : S = Q K^T * scale (MFMA) -> LDS bf16 (swizzled). barrier.
// Scan A  : x = S + mask, kept in REGISTERS (fp32); row max via shuffle.
// Scan B  : e = exp(x-mx) from regs -> LDS once; row sum via shuffle. barrier.
// Phase 2 : ctx = (e @ V) * inv, split-K over 2 wave-groups + LDS reduce.
// Scan C  : LAST: attn store p = e*inv (plain stores, drains at kernel end —
//           no mid-kernel store-drain barrier).
// ---------------------------------------------------------------------------
__device__ __forceinline__ int sw_off(int row, int col) {
    int unit = col >> 3;
    int slot = (unit + row) & 7;
    return row * 2048 + (((unit & ~7) | slot) << 3) + (col & 7);
}

__global__ __launch_bounds__(512, 4) void k_attn(
    const u16* __restrict__ Q, const u16* __restrict__ K,
    const u16* __restrict__ Vt, const void* __restrict__ mask,
    void* __restrict__ outbase, u16* __restrict__ ctx,
    const int* __restrict__ flag)
{
    __shared__ __align__(16) u16 sc[16 * 2048];   // 64 KB scores/e
    __shared__ __align__(16) float part[1024];    // 4 KB split-K partials
    __shared__ float invs[16];                    // per-row 1/sum
    const int isf32 = *flag;
    const int t = threadIdx.x;
    const int lane = t & 63, wave = t >> 6;
    const int quad = lane >> 4, l16 = lane & 15;
    const int q0 = blockIdx.x * 16;
    const int h = blockIdx.y, b = blockIdx.z;
    const int bh = b * 12 + h;
    const size_t mrow0 = ((size_t)bh * 2048 + q0) * 2048;
    const int row = t >> 5, j32 = t & 31;

    // ---- Mask prefetch: 64 floats, issued before phase 1 ----
    float mk[8][8];
#pragma unroll
    for (int i = 0; i < 8; i++)
        load8f_nt(mask, mrow0 + (size_t)row * 2048 + j32 * 8 + i * 256, isf32, mk[i]);

    const u16* Qb = Q + ((size_t)bh * 2048 + q0) * 64;
    const s16x8 qf0 = *(const s16x8*)&Qb[l16 * 64 + quad * 8];
    const s16x8 qf1 = *(const s16x8*)&Qb[l16 * 64 + 32 + quad * 8];
    const u16* Kb = K + (size_t)bh * 2048 * 64;

    // ---- Phase 1: scores -> LDS ----
#pragma unroll 4
    for (int it = 0; it < 16; it++) {
        const int kc = it * 128 + wave * 16;
        const u16* kp = &Kb[(size_t)(kc + l16) * 64 + quad * 8];
        s16x8 kf0 = *(const s16x8*)kp;
        s16x8 kf1 = *(const s16x8*)(kp + 32);
        f32x4 a = (f32x4){0.f, 0.f, 0.f, 0.f};
        a = MFMA16(qf0, kf0, a);
        a = MFMA16(qf1, kf1, a);
        const int col = kc + l16;
#pragma unroll
        for (int r = 0; r < 4; r++)
            sc[sw_off(quad * 4 + r, col)] = f2b(a[r] * 0.125f);
    }
    __syncthreads();

    // ---- Scan A: x = S + mask (kept in regs), row max ----
    float mx = -3.4e38f;
#pragma unroll
    for (int i = 0; i < 8; i++) {
        const int c0 = j32 * 8 + i * 256;
        s16x8 sv = *(const s16x8*)&sc[sw_off(row, c0)];
#pragma unroll
        for (int j = 0; j < 8; j++) {
            mk[i][j] += b2f((u16)sv[j]);
            mx = fmaxf(mx, mk[i][j]);
        }
    }
#pragma unroll
    for (int off = 16; off > 0; off >>= 1) mx = fmaxf(mx, __shfl_xor(mx, off));

    // ---- Scan B: e = exp(x - mx) -> LDS once, row sum ----
    float sum = 0.f;
#pragma unroll
    for (int i = 0; i < 8; i++) {
        const int c0 = j32 * 8 + i * 256;
        s16x8 nv;
#pragma unroll
        for (int j = 0; j < 8; j++) {
            float e = __expf(mk[i][j] - mx);
            nv[j] = (short)f2b(e);
            sum += e;
        }
        *(s16x8*)&sc[sw_off(row, c0)] = nv;
    }
#pragma unroll
    for (int off = 16; off > 0; off >>= 1) sum += __shfl_xor(sum, off);
    const float inv = 1.0f / sum;
    if (j32 == 0) invs[row] = inv;
    __syncthreads();

    // ---- Phase 2: ctx = (e @ V) * inv, split-K over wave groups ----
    const int wg = wave >> 2;                 // 0: kk 0..31, 1: kk 32..63
    const int dv = (wave & 3) * 16 + l16;
    const u16* vrow = Vt + ((size_t)bh * 64 + dv) * 2048;
    f32x4 o = (f32x4){0.f, 0.f, 0.f, 0.f};
    const int kbase = wg * 32;
#pragma unroll 4
    for (int kk = 0; kk < 32; kk++) {
        const int kcol = (kbase + kk) * 32 + quad * 8;
        s16x8 pa = *(const s16x8*)&sc[sw_off(l16, kcol)];
        s16x8 vb = *(const s16x8*)&vrow[kcol];
        o = MFMA16(pa, vb, o);
    }
    if (wg == 1) *(f32x4*)&part[((wave & 3) * 64 + lane) * 4] = o;
    __syncthreads();
    if (wg == 0) {
        f32x4 o2 = *(const f32x4*)&part[((wave & 3) * 64 + lane) * 4];
#pragma unroll
        for (int r = 0; r < 4; r++) {
            float val = (o[r] + o2[r]) * invs[quad * 4 + r];
            ctx[((size_t)b * 2048 + q0 + quad * 4 + r) * 768 + h * 64 + dv] = f2b(val);
        }
    }

    // ---- Scan C (last): global attn store, drains at kernel end ----
    const size_t aoff = 3145728 + mrow0 + (size_t)row * 2048;
#pragma unroll 2
    for (int i = 0; i < 8; i++) {
        const int c0 = j32 * 8 + i * 256;
        s16x8 sv = *(const s16x8*)&sc[sw_off(row, c0)];
        if (isf32) {
            float* arow = (float*)outbase + aoff;
            f32x4 lo, hi;
#pragma unroll
            for (int j = 0; j < 4; j++) lo[j] = b2f((u16)sv[j]) * inv;
#pragma unroll
            for (int j = 0; j < 4; j++) hi[j] = b2f((u16)sv[j + 4]) * inv;
            *(f32x4*)&arow[c0] = lo;
            *(f32x4*)&arow[c0 + 4] = hi;
        } else {
            u16* arow = (u16*)outbase + aoff;
            s16x8 pv;
#pragma unroll
            for (int j = 0; j < 8; j++) pv[j] = (short)f2b(b2f((u16)sv[j]) * inv);
            *(s16x8*)&arow[c0] = pv;
        }
    }
}

// ---------------------------------------------------------------------------
extern "C" void kernel_launch(void* const* d_in, const int* in_sizes, int n_in,
                              void* d_out, int out_size, void* d_ws, size_t ws_size,
                              hipStream_t stream) {
    const void* q    = d_in[0];
    const void* k    = d_in[1];
    const void* v    = d_in[2];
    const void* mask = d_in[3];
    const void* Wq   = d_in[4];
    const void* bq   = d_in[5];
    const void* Wk   = d_in[6];
    const void* bk   = d_in[7];
    const void* Wv   = d_in[8];
    const void* bv   = d_in[9];
    const void* Wo   = d_in[10];
    const void* bo   = d_in[11];

    u16* ws  = (u16*)d_ws;
    u16* WT  = ws;                       // 4 x 589824  (WqT,WkT,WvT,WoT)
    u16* Qb  = ws + 2359296;             // [2,12,2048,64]
    u16* Kb  = ws + 5505024;             // [2,12,2048,64]
    u16* Vtb = ws + 8650752;             // [2,12,64,2048]
    u16* ctx = ws + 11796480;            // [2,2048,768]
    int* flag = (int*)(ws + 14942208);   // dtype flag (1 => fp32 tensors)

    // Optional bf16 pre-converted q/k/v (guarded by workspace size)
    u16* Qc = ws + 14942224;             // 3 x 3145728 u16
    u16* Kc = Qc + 3145728;
    u16* Vc = Kc + 3145728;
    const int use_cvt = (ws_size >= (size_t)48758816) ? 1 : 0;

    k_detect<<<1, 64, 0, stream>>>((const u16*)q, flag);
    k_transpose<<<dim3(12, 12, 4), 256, 0, stream>>>(Wq, Wk, Wv, Wo, WT, flag);
    if (use_cvt) {
        k_cvt<<<dim3(1536, 3), 256, 0, stream>>>(q, k, v, Qc, Kc, Vc, flag);
        k_qkv<<<dim3(32, 12, 3), 256, 0, stream>>>(Qc, Kc, Vc, WT, bq, bk, bv,
                                                   Qb, Kb, Vtb, flag, 1);
    } else {
        k_qkv<<<dim3(32, 12, 3), 256, 0, stream>>>(q, k, v, WT, bq, bk, bv,
                                                   Qb, Kb, Vtb, flag, 0);
    }
    k_attn<<<dim3(128, 12, 2), 512, 0, stream>>>(Qb, Kb, Vtb, mask, d_out, ctx, flag);
    k_oproj<<<dim3(32, 12, 1), 256, 0, stream>>>(ctx, WT + 3 * 589824, bo, d_out, flag);
}